// Round 1
// baseline (258.555 us; speedup 1.0000x reference)
//
#include <hip/hip_runtime.h>

#define T_STEPS 256
#define F_IN 64

typedef __bf16 bf16x8 __attribute__((ext_vector_type(8)));
typedef float f32x4 __attribute__((ext_vector_type(4)));

__device__ __forceinline__ float sigmoid_f(float x) {
    // 1/(1+2^(-x*log2e)) ; v_exp_f32 is exp2
    return __builtin_amdgcn_rcpf(1.0f + __builtin_amdgcn_exp2f(-1.44269504f * x));
}
__device__ __forceinline__ float tanh_f(float x) {
    // tanh(x) = 1 - 2/(1+2^(x*2*log2e)) ; saturates correctly at +/-inf
    return 1.0f - 2.0f * __builtin_amdgcn_rcpf(1.0f + __builtin_amdgcn_exp2f(2.88539008f * x));
}

// Per wave: 16 batch rows, full 128-gate tile, all T steps.
// MFMA 16x16x32 bf16, fp32 accum; c/h state fp32 in registers.
// A-frag: elem j of lane l -> A[row=l&15][k=(l>>4)*8+j]
// B-frag: elem j of lane l -> B[k=(l>>4)*8+j][col=l&15]
// D     : elem r of lane l -> D[row=(l>>4)*4+r][col=l&15]
__global__ __launch_bounds__(256, 1)
void lstm_fused(const float* __restrict__ x,
                const float* __restrict__ Wl,   // [96][128]
                const float* __restrict__ bl,   // [128]
                const float* __restrict__ Wd,   // [32]
                const float* __restrict__ bd,   // [1]
                float* __restrict__ out)        // [B]
{
    __shared__ __align__(16) __bf16 h_all[4][16][32];   // 4 KB, per-wave private slices
    const int lane = threadIdx.x & 63;
    const int wid  = threadIdx.x >> 6;
    const int cl   = lane & 15;
    const int g4   = lane >> 4;                 // 0..3
    const int rowBase = blockIdx.x * 64 + wid * 16;

    __bf16 (*h_buf)[32] = h_all[wid];

    // ---- W fragments in registers (loaded once; L2-served, one-time cost) ----
    // wfrag[kc][cf] elem j = W[kc*32 + g4*8 + j][cf*16 + cl]
    bf16x8 wfrag[3][8];
#pragma unroll
    for (int kc = 0; kc < 3; ++kc) {
#pragma unroll
        for (int cf = 0; cf < 8; ++cf) {
            bf16x8 v;
#pragma unroll
            for (int j = 0; j < 8; ++j)
                v[j] = (__bf16)Wl[(kc * 32 + g4 * 8 + j) * 128 + cf * 16 + cl];
            wfrag[kc][cf] = v;
        }
    }

    float bias[8];
#pragma unroll
    for (int cf = 0; cf < 8; ++cf) bias[cf] = bl[cf * 16 + cl];

    const float wd0 = Wd[cl], wd1 = Wd[cl + 16];
    const float bdv = bd[0];

    // zero this wave's h buffer (h0 = 0)
    *reinterpret_cast<f32x4*>(reinterpret_cast<char*>(&h_buf[0][0]) + lane * 16) =
        f32x4{0.f, 0.f, 0.f, 0.f};
    asm volatile("s_waitcnt lgkmcnt(0)" ::: "memory");

    float c_st[2][4] = {{0.f,0.f,0.f,0.f},{0.f,0.f,0.f,0.f}};
    float h_last[2][4];

    const float* xrow = x + (size_t)(rowBase + cl) * (size_t)(T_STEPS * F_IN);

    // x register double buffers: per lane 16 fp32 per step (2 A-frags worth)
    f32x4 xa[4], xb[4];

#define LOAD_X(BUF, TT) do {                                                  \
        const float* _p = xrow + (TT) * F_IN + g4 * 8;                        \
        BUF[0] = *reinterpret_cast<const f32x4*>(_p);                         \
        BUF[1] = *reinterpret_cast<const f32x4*>(_p + 4);                     \
        BUF[2] = *reinterpret_cast<const f32x4*>(_p + 32);                    \
        BUF[3] = *reinterpret_cast<const f32x4*>(_p + 36);                    \
    } while (0)

#define STEP(TT, XCUR) do {                                                   \
        /* convert current x to bf16 A-frags */                               \
        bf16x8 ax0, ax1;                                                      \
        _Pragma("unroll")                                                     \
        for (int j = 0; j < 4; ++j) {                                         \
            ax0[j]     = (__bf16)XCUR[0][j];                                  \
            ax0[4 + j] = (__bf16)XCUR[1][j];                                  \
            ax1[j]     = (__bf16)XCUR[2][j];                                  \
            ax1[4 + j] = (__bf16)XCUR[3][j];                                  \
        }                                                                     \
        /* prefetch t+2 into the just-freed buffer */                         \
        if ((TT) + 2 < T_STEPS) { LOAD_X(XCUR, (TT) + 2); }                   \
        /* h A-frag from LDS (written end of previous step) */                \
        bf16x8 ah = *reinterpret_cast<bf16x8*>(&h_buf[cl][g4 * 8]);           \
        f32x4 acc[8];                                                         \
        _Pragma("unroll")                                                     \
        for (int cf = 0; cf < 8; ++cf) {                                      \
            f32x4 a = {bias[cf], bias[cf], bias[cf], bias[cf]};               \
            a = __builtin_amdgcn_mfma_f32_16x16x32_bf16(ax0, wfrag[0][cf], a, 0, 0, 0); \
            a = __builtin_amdgcn_mfma_f32_16x16x32_bf16(ax1, wfrag[1][cf], a, 0, 0, 0); \
            a = __builtin_amdgcn_mfma_f32_16x16x32_bf16(ah,  wfrag[2][cf], a, 0, 0, 0); \
            acc[cf] = a;                                                      \
        }                                                                     \
        /* elementwise LSTM cell: lane owns rows g4*4+r, units cl and cl+16 */\
        _Pragma("unroll")                                                     \
        for (int half = 0; half < 2; ++half) {                                \
            _Pragma("unroll")                                                 \
            for (int r = 0; r < 4; ++r) {                                     \
                float gi = acc[0 + half][r];                                  \
                float gj = acc[2 + half][r];                                  \
                float gf = acc[4 + half][r];                                  \
                float go = acc[6 + half][r];                                  \
                float sf = sigmoid_f(gf + 1.0f);                              \
                float si = sigmoid_f(gi);                                     \
                float tj = tanh_f(gj);                                        \
                float cn = c_st[half][r] * sf + si * tj;                      \
                float tc = tanh_f(cn);                                        \
                float so = sigmoid_f(go);                                     \
                float hh = tc * so;                                           \
                c_st[half][r] = cn;                                           \
                h_last[half][r] = hh;                                         \
                h_buf[g4 * 4 + r][half * 16 + cl] = (__bf16)hh;               \
            }                                                                 \
        }                                                                     \
        asm volatile("s_waitcnt lgkmcnt(0)" ::: "memory");                    \
    } while (0)

    LOAD_X(xa, 0);
    LOAD_X(xb, 1);

    for (int t = 0; t < T_STEPS; t += 2) {
        STEP(t, xa);
        STEP(t + 1, xb);
    }

    // ---- epilogue: out[row] = ELU(h_T . Wd + bd) ----
    float s[4];
#pragma unroll
    for (int r = 0; r < 4; ++r) {
        float v = h_last[0][r] * wd0 + h_last[1][r] * wd1;
#pragma unroll
        for (int m = 1; m < 16; m <<= 1) v += __shfl_xor(v, m, 64);
        s[r] = v;
    }
    if (cl == 0) {
#pragma unroll
        for (int r = 0; r < 4; ++r) {
            float z = s[r] + bdv;
            out[rowBase + g4 * 4 + r] = z > 0.f ? z : (__expf(z) - 1.0f);
        }
    }
#undef STEP
#undef LOAD_X
}

extern "C" void kernel_launch(void* const* d_in, const int* in_sizes, int n_in,
                              void* d_out, int out_size, void* d_ws, size_t ws_size,
                              hipStream_t stream) {
    const float* x  = (const float*)d_in[0];
    const float* Wl = (const float*)d_in[1];
    const float* bl = (const float*)d_in[2];
    const float* Wd = (const float*)d_in[3];
    const float* bd = (const float*)d_in[4];
    float* out = (float*)d_out;

    const int rows = out_size;              // B
    const int grid = (rows + 63) / 64;      // 64 rows per 256-thread block
    hipLaunchKernelGGL(lstm_fused, dim3(grid), dim3(256), 0, stream,
                       x, Wl, bl, Wd, bd, out);
}

// Round 2
// 257.473 us; speedup vs baseline: 1.0042x; 1.0042x over previous
//
#include <hip/hip_runtime.h>
#include <stdint.h>

#define T_STEPS 256
#define F_IN 64
#define L2E 1.44269504f

typedef __bf16 bf16x8 __attribute__((ext_vector_type(8)));
typedef float f32x4 __attribute__((ext_vector_type(4)));
typedef uint32_t u32;
typedef uint32_t u32x4 __attribute__((ext_vector_type(4)));

#define GLDS16(gp, lp)                                                         \
    __builtin_amdgcn_global_load_lds(                                          \
        (const __attribute__((address_space(1))) unsigned int*)(gp),           \
        (__attribute__((address_space(3))) unsigned int*)(lp), 16, 0, 0)

__device__ __forceinline__ u32 pk2(float lo, float hi) {
    unsigned short a = __builtin_bit_cast(unsigned short, (__bf16)lo);
    unsigned short b = __builtin_bit_cast(unsigned short, (__bf16)hi);
    return (u32)a | ((u32)b << 16);
}

// Transposed formulation: gates^T[128][16] = W^T[128][96] @ [x|h]^T[96][16]
// A-frag (W^T): elem j of lane l -> W^T[gate=gt*16+(l&15)][k=(l>>4)*8+j]
// B-frag (x/h): elem j of lane l -> [x|h]^T[k=(l>>4)*8+j][batch=l&15]
// D          : elem r of lane l -> gates^T[gate=gt*16+(l>>4)*4+r][batch=l&15]
__global__ __launch_bounds__(256, 1)
void lstm_fused(const float* __restrict__ x,
                const float* __restrict__ Wl,   // [96][128]
                const float* __restrict__ bl,   // [128]
                const float* __restrict__ Wd,   // [32]
                const float* __restrict__ bd,   // [1]
                float* __restrict__ out)        // [B]
{
    // x staging ring: [wave][slot][4KB = 4 k-blocks x 16 rows x 64B]
    __shared__ __align__(16) float xlds[4][4][1024];
    const int lane = threadIdx.x & 63;
    const int wid  = threadIdx.x >> 6;
    const int cl   = lane & 15;     // gate-in-tile for A/D, batch col for B/D
    const int g4   = lane >> 4;
    const int rowBase = blockIdx.x * 64 + wid * 16;

    // ---- W^T A-fragments (register contents identical to round-1's B-frags) ----
    bf16x8 wfrag[3][8];
#pragma unroll
    for (int kc = 0; kc < 3; ++kc) {
#pragma unroll
        for (int gt = 0; gt < 8; ++gt) {
            bf16x8 v;
#pragma unroll
            for (int j = 0; j < 8; ++j)
                v[j] = (__bf16)Wl[(kc * 32 + g4 * 8 + j) * 128 + gt * 16 + cl];
            wfrag[kc][gt] = v;
        }
    }

    // ---- bias folded into activation constants (per-lane, unit u = uh*16+g4*4+r) ----
    float KI[2][4], KJ[2][4], KF[2][4], KO[2][4];
#pragma unroll
    for (int uh = 0; uh < 2; ++uh) {
        f32x4 bi = *(const f32x4*)(bl +   0 + uh * 16 + g4 * 4);
        f32x4 bj = *(const f32x4*)(bl +  32 + uh * 16 + g4 * 4);
        f32x4 bf = *(const f32x4*)(bl +  64 + uh * 16 + g4 * 4);
        f32x4 bo = *(const f32x4*)(bl +  96 + uh * 16 + g4 * 4);
#pragma unroll
        for (int r = 0; r < 4; ++r) {
            KI[uh][r] = -L2E * bi[r];
            KJ[uh][r] =  2.0f * L2E * bj[r];
            KF[uh][r] = -L2E * (bf[r] + 1.0f);   // forget bias folded too
            KO[uh][r] = -L2E * bo[r];
        }
    }
    const f32x4 wdv0 = *(const f32x4*)(Wd + g4 * 4);
    const f32x4 wdv1 = *(const f32x4*)(Wd + 16 + g4 * 4);
    const float bd0 = bd[0];

    // ---- per-lane pre-swizzled global base for coalesced x fetch ----
    // lane l fetches row (l>>2), 16B chunk (l&3)^((row)&... (row>>1)&3) of each 64B block
    const float* gbase = x + (size_t)(rowBase + (lane >> 2)) * (size_t)(T_STEPS * F_IN)
                           + (size_t)(((lane & 3) ^ ((lane >> 3) & 3)) * 4);

    // reader-side swizzled LDS offsets (floats). swz(row=cl) = (cl>>1)&3
    const int swz = (cl >> 1) & 3;
    const int c0  = ((g4 & 1) * 2)     ^ swz;
    const int c1  = ((g4 & 1) * 2 + 1) ^ swz;
    const int kA  = (g4 >> 1) * 256 + cl * 16;  // k-block g4>>1, row cl
    const int kB  = kA + 512;                   // k-block +2

    // drain setup loads so vmcnt counting is exact
    asm volatile("s_waitcnt vmcnt(0)" ::: "memory");
    __builtin_amdgcn_sched_barrier(0);

    // ---- prologue prefetch: steps 0..2 -> slots 0..2 ----
#pragma unroll
    for (int s = 0; s < 3; ++s) {
        const float* gp = gbase + s * F_IN;
        GLDS16(gp,      &xlds[wid][s][0]);
        GLDS16(gp + 16, &xlds[wid][s][256]);
        GLDS16(gp + 32, &xlds[wid][s][512]);
        GLDS16(gp + 48, &xlds[wid][s][768]);
    }

    const f32x4 z4 = {0.f, 0.f, 0.f, 0.f};
    float c_st[2][4] = {{0.f,0.f,0.f,0.f},{0.f,0.f,0.f,0.f}};
    float hl[2][4]   = {{0.f,0.f,0.f,0.f},{0.f,0.f,0.f,0.f}};
    u32x4 ahw = {0u, 0u, 0u, 0u};               // h0 = 0

    const int srcA = cl + 32 * (g4 & 1);
    const int srcB = srcA + 16;
    const int sel  = g4 >> 1;

#define STEP(TT, SLOT) do {                                                    \
    const int tpf = ((TT) + 3 < T_STEPS) ? (TT) + 3 : T_STEPS - 1;             \
    const float* gp = gbase + tpf * F_IN;                                      \
    GLDS16(gp,      &xlds[wid][((SLOT)+3)&3][0]);                              \
    GLDS16(gp + 16, &xlds[wid][((SLOT)+3)&3][256]);                            \
    GLDS16(gp + 32, &xlds[wid][((SLOT)+3)&3][512]);                            \
    GLDS16(gp + 48, &xlds[wid][((SLOT)+3)&3][768]);                            \
    asm volatile("s_waitcnt vmcnt(12)" ::: "memory");                          \
    __builtin_amdgcn_sched_barrier(0);                                         \
    const float* sl = &xlds[wid][SLOT][0];                                     \
    f32x4 xr0 = *(const f32x4*)(sl + kA + c0 * 4);                             \
    f32x4 xr1 = *(const f32x4*)(sl + kA + c1 * 4);                             \
    f32x4 xr2 = *(const f32x4*)(sl + kB + c0 * 4);                             \
    f32x4 xr3 = *(const f32x4*)(sl + kB + c1 * 4);                             \
    bf16x8 ax0, ax1;                                                           \
    _Pragma("unroll")                                                          \
    for (int j = 0; j < 4; ++j) {                                              \
        ax0[j]     = (__bf16)xr0[j];                                           \
        ax0[4 + j] = (__bf16)xr1[j];                                           \
        ax1[j]     = (__bf16)xr2[j];                                           \
        ax1[4 + j] = (__bf16)xr3[j];                                           \
    }                                                                          \
    bf16x8 ah = __builtin_bit_cast(bf16x8, ahw);                               \
    f32x4 acc[8];                                                              \
    _Pragma("unroll")                                                          \
    for (int gt = 0; gt < 8; ++gt) {                                           \
        f32x4 a = __builtin_amdgcn_mfma_f32_16x16x32_bf16(wfrag[0][gt], ax0, z4, 0, 0, 0); \
        a = __builtin_amdgcn_mfma_f32_16x16x32_bf16(wfrag[1][gt], ax1, a, 0, 0, 0);        \
        a = __builtin_amdgcn_mfma_f32_16x16x32_bf16(wfrag[2][gt], ah,  a, 0, 0, 0);        \
        acc[gt] = a;                                                           \
    }                                                                          \
    _Pragma("unroll")                                                          \
    for (int uh = 0; uh < 2; ++uh) {                                           \
        _Pragma("unroll")                                                      \
        for (int r = 0; r < 4; ++r) {                                          \
            float gi = acc[uh][r];                                             \
            float gj = acc[2 + uh][r];                                         \
            float gf = acc[4 + uh][r];                                         \
            float go = acc[6 + uh][r];                                         \
            float sf = __builtin_amdgcn_rcpf(1.0f + __builtin_amdgcn_exp2f(__builtin_fmaf(gf, -L2E, KF[uh][r]))); \
            float si = __builtin_amdgcn_rcpf(1.0f + __builtin_amdgcn_exp2f(__builtin_fmaf(gi, -L2E, KI[uh][r]))); \
            float tj = 1.0f - 2.0f * __builtin_amdgcn_rcpf(1.0f + __builtin_amdgcn_exp2f(__builtin_fmaf(gj, 2.0f * L2E, KJ[uh][r]))); \
            float cn = __builtin_fmaf(c_st[uh][r], sf, si * tj);               \
            float tc = 1.0f - 2.0f * __builtin_amdgcn_rcpf(1.0f + __builtin_amdgcn_exp2f(2.0f * L2E * cn)); \
            float so = __builtin_amdgcn_rcpf(1.0f + __builtin_amdgcn_exp2f(__builtin_fmaf(go, -L2E, KO[uh][r]))); \
            float hh = tc * so;                                                \
            c_st[uh][r] = cn;                                                  \
            hl[uh][r] = hh;                                                    \
        }                                                                      \
    }                                                                          \
    u32 P0 = pk2(hl[0][0], hl[0][1]);                                          \
    u32 P1 = pk2(hl[0][2], hl[0][3]);                                          \
    u32 P2 = pk2(hl[1][0], hl[1][1]);                                          \
    u32 P3 = pk2(hl[1][2], hl[1][3]);                                          \
    int A0 = __shfl((int)P0, srcA, 64), A1 = __shfl((int)P1, srcA, 64);        \
    int A2 = __shfl((int)P2, srcA, 64), A3 = __shfl((int)P3, srcA, 64);        \
    int B0 = __shfl((int)P0, srcB, 64), B1 = __shfl((int)P1, srcB, 64);        \
    int B2 = __shfl((int)P2, srcB, 64), B3 = __shfl((int)P3, srcB, 64);        \
    ahw[0] = (u32)(sel ? A2 : A0);                                             \
    ahw[1] = (u32)(sel ? A3 : A1);                                             \
    ahw[2] = (u32)(sel ? B2 : B0);                                             \
    ahw[3] = (u32)(sel ? B3 : B1);                                             \
} while (0)

    for (int t = 0; t < T_STEPS; t += 4) {
        STEP(t,     0);
        STEP(t + 1, 1);
        STEP(t + 2, 2);
        STEP(t + 3, 3);
    }
#undef STEP

    // ---- epilogue: out[batch cl] = ELU(sum_u h[u]*Wd[u] + bd) ----
    float v = 0.f;
#pragma unroll
    for (int r = 0; r < 4; ++r) {
        v = __builtin_fmaf(hl[0][r], wdv0[r], v);
        v = __builtin_fmaf(hl[1][r], wdv1[r], v);
    }
    v += __shfl_xor(v, 16, 64);
    v += __shfl_xor(v, 32, 64);
    if (lane < 16) {
        float z = v + bd0;
        out[rowBase + lane] = z > 0.f ? z : (__expf(z) - 1.0f);
    }
}

extern "C" void kernel_launch(void* const* d_in, const int* in_sizes, int n_in,
                              void* d_out, int out_size, void* d_ws, size_t ws_size,
                              hipStream_t stream) {
    const float* x  = (const float*)d_in[0];
    const float* Wl = (const float*)d_in[1];
    const float* bl = (const float*)d_in[2];
    const float* Wd = (const float*)d_in[3];
    const float* bd = (const float*)d_in[4];
    float* out = (float*)d_out;

    const int rows = out_size;              // B = 16384
    const int grid = (rows + 63) / 64;      // 64 rows per 256-thread block
    hipLaunchKernelGGL(lstm_fused, dim3(grid), dim3(256), 0, stream,
                       x, Wl, bl, Wd, bd, out);
}